// Round 7
// baseline (1644.797 us; speedup 1.0000x reference)
//
#include <hip/hip_runtime.h>
#include <stdint.h>

// MemoryModule: z[N=65536,D=256], memory[M=2000,D=256] (fp32)
//   z_norm, m_norm = row-L2-normalize (eps added to norm)
//   sim = z_norm @ m_norm^T; w = softmax(sim, axis=1)
//   w2 = relu(w-lamb)*w/(|w-lamb|+1e-12); w_hat = w2/(sum w2 + 1e-12)
//   z_hat = w_hat @ memory
// d_out = [z_hat (N*D) | w_hat (N*M)] fp32
//
// R6: identical body to R5; ONLY change is __launch_bounds__(256,3)->(256,6).
// Evidence: measured occupancy tracks the launch-bounds arg across all
// rounds (2->1.9, 3->2.5, 4->3.7, 5->4.2 blocks/CU) and traffic rate tracks
// residency (1.23 -> 2.48 TB/s). Kernel is MLP-bound; raise residency.
// Softmax max-subtraction dropped: |sim|<=1 (cosine), exp in [e^-1, e].

typedef float  f32x4  __attribute__((ext_vector_type(4)));
typedef __bf16 bf16x8 __attribute__((ext_vector_type(8)));

#define DDIM 256
#define MDIM 2000
#define MT   125          // 2000 / 16 m-tiles
#define MPAD 2048
#define NROWS 32          // z-rows per block (2 row-groups of 16)
#define LAMB 0.002f
#define EPS_NORM 1e-10f
#define EPS_SHRINK 1e-12f

// ---------------- kernel 1: memory -> bf16 m_norm (padded to MPAD rows) ----
__global__ __launch_bounds__(256) void norm_mem_k(const float* __restrict__ mem,
                                                  __bf16* __restrict__ mnorm) {
  const int row = blockIdx.x;
  const int t   = threadIdx.x;
  if (row >= MDIM) { mnorm[(size_t)row * DDIM + t] = (__bf16)0.0f; return; }
  float x = mem[(size_t)row * DDIM + t];
  float s = x * x;
  #pragma unroll
  for (int m = 1; m < 64; m <<= 1) s += __shfl_xor(s, m, 64);
  __shared__ float wsum[4];
  if ((t & 63) == 0) wsum[t >> 6] = s;
  __syncthreads();
  s = wsum[0] + wsum[1] + wsum[2] + wsum[3];
  const float scale = 1.0f / (sqrtf(s) + EPS_NORM);
  mnorm[(size_t)row * DDIM + t] = (__bf16)(x * scale);
}

// ---------------- kernel 2: fused, 32 rows/block, 2 sweeps ----------------
// 4 waves split 125 m-tiles contiguously (32/32/32/29). Per tile:
// B[8] (16 rows x K=256 bf16) from L2, MFMA vs 2 row-group A-frags (regs).
// MFMA C layout (16x16x32): col = lane&15 (m), row = quad*4 + reg (n).
__global__ __launch_bounds__(256, 6) void fused_k(
    const float* __restrict__ z, const __bf16* __restrict__ mnorm,
    const float* __restrict__ mem, float* __restrict__ outz,
    float* __restrict__ outw) {
  __shared__ __bf16 zs[NROWS][264];      // z_norm staging (+8 pad)  16.9 KB
  __shared__ float  red[4][NROWS];
  __shared__ float  Srow[NROWS];
  __shared__ float  S2row[NROWS];

  const int tid  = threadIdx.x;
  const int n0   = blockIdx.x * NROWS;
  const int lane = tid & 63;
  const int wave = tid >> 6;
  const int quad = lane >> 4;
  const int col  = lane & 15;

  // ---- phase 1: z_norm -> zs ----
  {
    const int r  = tid >> 3;
    const int c0 = (tid & 7) * 32;
    const float* zp = z + (size_t)(n0 + r) * DDIM + c0;
    float v[32];
    #pragma unroll
    for (int k = 0; k < 8; ++k) {
      const float4 q = *(const float4*)(zp + 4 * k);
      v[4*k+0] = q.x; v[4*k+1] = q.y; v[4*k+2] = q.z; v[4*k+3] = q.w;
    }
    float s = 0.f;
    #pragma unroll
    for (int k = 0; k < 32; ++k) s += v[k] * v[k];
    #pragma unroll
    for (int m = 1; m < 8; m <<= 1) s += __shfl_xor(s, m, 64);
    const float scale = 1.0f / (sqrtf(s) + EPS_NORM);
    #pragma unroll
    for (int k = 0; k < 32; ++k) zs[r][c0 + k] = (__bf16)(v[k] * scale);
  }

  // ---- zero this block's z_hat rows (cold path atomically adds later) ----
  {
    const f32x4 zero4 = {0.f, 0.f, 0.f, 0.f};
    f32x4* oz = (f32x4*)(outz + (size_t)n0 * DDIM);
    #pragma unroll
    for (int k = 0; k < 8; ++k) oz[tid + 256 * k] = zero4;
  }
  __syncthreads();

  // ---- A fragments for both row-groups ----
  bf16x8 af[2][8];
  #pragma unroll
  for (int rg = 0; rg < 2; ++rg)
    #pragma unroll
    for (int kc = 0; kc < 8; ++kc)
      af[rg][kc] = *(const bf16x8*)&zs[rg * 16 + col][kc * 32 + quad * 8];

  const int t0    = wave * 32;
  const int ntile = (MT - t0) < 32 ? (MT - t0) : 32;   // 32,32,32,29

  // ---- sweep 1: S = sum(exp(sim)) per row ----
  float S[2][4] = {{0.f,0.f,0.f,0.f},{0.f,0.f,0.f,0.f}};
  for (int i = 0; i < ntile; ++i) {
    const int t = t0 + i;
    const __bf16* bp = mnorm + (size_t)(t * 16 + col) * DDIM + quad * 8;
    bf16x8 b[8];
    #pragma unroll
    for (int kc = 0; kc < 8; ++kc) b[kc] = *(const bf16x8*)(bp + kc * 32);
    #pragma unroll
    for (int rg = 0; rg < 2; ++rg) {
      f32x4 c = (f32x4){0.f, 0.f, 0.f, 0.f};
      #pragma unroll
      for (int kc = 0; kc < 8; ++kc)
        c = __builtin_amdgcn_mfma_f32_16x16x32_bf16(af[rg][kc], b[kc], c, 0, 0, 0);
      #pragma unroll
      for (int j = 0; j < 4; ++j) S[rg][j] += __expf(c[j]);
    }
  }
  #pragma unroll
  for (int rg = 0; rg < 2; ++rg)
    #pragma unroll
    for (int j = 0; j < 4; ++j) {
      #pragma unroll
      for (int m = 1; m < 16; m <<= 1) S[rg][j] += __shfl_xor(S[rg][j], m, 64);
      if (col == 0) red[wave][rg * 16 + quad * 4 + j] = S[rg][j];
    }
  __syncthreads();
  if (tid < NROWS) Srow[tid] = red[0][tid] + red[1][tid] + red[2][tid] + red[3][tid];
  __syncthreads();

  float invS[2][4];
  #pragma unroll
  for (int rg = 0; rg < 2; ++rg)
    #pragma unroll
    for (int j = 0; j < 4; ++j) invS[rg][j] = 1.0f / Srow[rg * 16 + quad * 4 + j];

  // ---- sweep 2: recompute sim; w2 + S2 + store w2 (== w_hat if S2==0) ----
  float S2[2][4] = {{0.f,0.f,0.f,0.f},{0.f,0.f,0.f,0.f}};
  for (int i = 0; i < ntile; ++i) {
    const int t = t0 + i;
    const __bf16* bp = mnorm + (size_t)(t * 16 + col) * DDIM + quad * 8;
    bf16x8 b[8];
    #pragma unroll
    for (int kc = 0; kc < 8; ++kc) b[kc] = *(const bf16x8*)(bp + kc * 32);
    #pragma unroll
    for (int rg = 0; rg < 2; ++rg) {
      f32x4 c = (f32x4){0.f, 0.f, 0.f, 0.f};
      #pragma unroll
      for (int kc = 0; kc < 8; ++kc)
        c = __builtin_amdgcn_mfma_f32_16x16x32_bf16(af[rg][kc], b[kc], c, 0, 0, 0);
      float* orow = outw + (size_t)(n0 + rg * 16 + quad * 4) * MDIM + t * 16 + col;
      #pragma unroll
      for (int j = 0; j < 4; ++j) {
        const float w = __expf(c[j]) * invS[rg][j];
        const float d = w - LAMB;
        const float w2 = (d > 0.f) ? (d * w / (d + EPS_SHRINK)) : 0.f;
        S2[rg][j] += w2;
        orow[(size_t)j * MDIM] = w2;
      }
    }
  }
  #pragma unroll
  for (int rg = 0; rg < 2; ++rg)
    #pragma unroll
    for (int j = 0; j < 4; ++j) {
      #pragma unroll
      for (int m = 1; m < 16; m <<= 1) S2[rg][j] += __shfl_xor(S2[rg][j], m, 64);
      if (col == 0) red[wave][rg * 16 + quad * 4 + j] = S2[rg][j];
    }
  __syncthreads();
  if (tid < NROWS) S2row[tid] = red[0][tid] + red[1][tid] + red[2][tid] + red[3][tid];
  __syncthreads();

  float totS2 = 0.f;
  #pragma unroll
  for (int r = 0; r < NROWS; ++r) totS2 += S2row[r];

  // ---- cold path: only if some weight survived shrink (exact general case).
  // Re-read stored w2, scale to w_hat, rewrite; accumulate z_hat via global
  // atomics into the pre-zeroed outz rows (block-local rows, no races).
  if (totS2 > 0.f) {
    #pragma unroll 1
    for (int i = 0; i < ntile; ++i) {
      const int t = t0 + i;
      #pragma unroll 1
      for (int rg = 0; rg < 2; ++rg)
        #pragma unroll 1
        for (int j = 0; j < 4; ++j) {
          const int r = rg * 16 + quad * 4 + j;
          const float rs2 = 1.0f / (S2row[r] + EPS_SHRINK);
          const int mcol = t * 16 + col;
          float* p = outw + (size_t)(n0 + r) * MDIM + mcol;
          const float wh = *p * rs2;   // rows w/ S2==0: 0 * big == 0, exact
          *p = wh;
          if (wh != 0.f) {
            const float* mrow = mem + (size_t)mcol * DDIM;
            float* zr = outz + (size_t)(n0 + r) * DDIM;
            #pragma unroll 1
            for (int dd = 0; dd < DDIM; ++dd) atomicAdd(&zr[dd], wh * mrow[dd]);
          }
        }
    }
  }
}

extern "C" void kernel_launch(void* const* d_in, const int* in_sizes, int n_in,
                              void* d_out, int out_size, void* d_ws, size_t ws_size,
                              hipStream_t stream) {
  const float* z   = (const float*)d_in[0];
  const float* mem = (const float*)d_in[1];
  const int N = in_sizes[0] / DDIM;           // 65536
  float* outz = (float*)d_out;                // [N, D]
  float* outw = outz + (size_t)N * DDIM;      // [N, M]
  __bf16* mnorm = (__bf16*)d_ws;              // [MPAD, D] bf16 = 1 MiB

  hipLaunchKernelGGL(norm_mem_k, dim3(MPAD), dim3(DDIM), 0, stream, mem, mnorm);
  hipLaunchKernelGGL(fused_k, dim3(N / NROWS), dim3(256), 0, stream,
                     z, mnorm, mem, outz, outw);
}

// Round 8
// 768.980 us; speedup vs baseline: 2.1389x; 2.1389x over previous
//
#include <hip/hip_runtime.h>
#include <stdint.h>

// MemoryModule: z[N=65536,D=256], memory[M=2000,D=256] (fp32)
//   z_norm, m_norm = row-L2-normalize (eps added to norm)
//   sim = z_norm @ m_norm^T; w = softmax(sim, axis=1)
//   w2 = relu(w-lamb)*w/(|w-lamb|+1e-12); w_hat = w2/(sum w2 + 1e-12)
//   z_hat = w_hat @ memory
// d_out = [z_hat (N*D) | w_hat (N*M)] fp32
//
// R7: single GEMM sweep (fp8 e4m3 operands, x16 scale, sim = c/256) tracking
// per-row sum(exp) AND max(sim). A row has any nonzero shrink output iff
// exp(max)/S > lamb; if no row in the block triggers (3x margin for this
// data), outputs are exact zeros -> coalesced nt zero-fill. Full per-element
// recompute kept as rare path. B-tile prefetch breaks load->MFMA serial chain.

typedef float f32x4 __attribute__((ext_vector_type(4)));

#define DDIM 256
#define MDIM 2000
#define MT   125          // 2000 / 16 m-tiles (exactly, no pad tiles)
#define NROWS 32          // z-rows per block (2 row-groups of 16)
#define LAMB 0.002f
#define EPS_NORM 1e-10f
#define EPS_SHRINK 1e-12f
#define INV256 0.00390625f

// ---- kernel 1: memory -> fp8 e4m3 m_norm, scaled x16. 1 row/wave ----------
__global__ __launch_bounds__(256) void norm_mem_k(const float* __restrict__ mem,
                                                  uint32_t* __restrict__ mnorm) {
  const int row  = blockIdx.x * 4 + (threadIdx.x >> 6);
  const int lane = threadIdx.x & 63;
  const float4 v = *(const float4*)(mem + (size_t)row * DDIM + lane * 4);
  float s = v.x * v.x + v.y * v.y + v.z * v.z + v.w * v.w;
  #pragma unroll
  for (int m = 1; m < 64; m <<= 1) s += __shfl_xor(s, m, 64);
  const float scale = 16.0f / (sqrtf(s) + EPS_NORM);
  int p = __builtin_amdgcn_cvt_pk_fp8_f32(v.x * scale, v.y * scale, 0, false);
  p     = __builtin_amdgcn_cvt_pk_fp8_f32(v.z * scale, v.w * scale, p, true);
  mnorm[(size_t)row * 64 + lane] = (uint32_t)p;
}

// ---- kernel 2: fused, 32 rows/block, one fp8 sweep + flag + fill ----------
// 4 waves split 125 m-tiles contiguously (32/32/32/29). Per tile: B[8]
// (16 rows x K=256 fp8) from L2 w/ prefetch, 16 MFMA fp8 vs 2 row-groups.
// MFMA C layout (16x16x32): col = lane&15 (m), row = quad*4 + reg (n).
__global__ __launch_bounds__(256, 4) void fused_k(
    const float* __restrict__ z, const uint8_t* __restrict__ mnorm,
    const float* __restrict__ mem, float* __restrict__ outz,
    float* __restrict__ outw) {
  __shared__ int   zs[NROWS][66];     // fp8 z_norm x16; 264B rows (8-aligned)
  __shared__ float redS[4][NROWS];
  __shared__ float redM[4][NROWS];
  __shared__ float Srow[NROWS];
  __shared__ float S2row[NROWS];
  __shared__ int   anyflag;

  const int tid  = threadIdx.x;
  const int n0   = blockIdx.x * NROWS;
  const int lane = tid & 63;
  const int wave = tid >> 6;
  const int quad = lane >> 4;
  const int col  = lane & 15;

  if (tid == 0) anyflag = 0;

  // ---- phase 1: z_norm -> zs as fp8 x16 ----
  {
    const int r  = tid >> 3;
    const int c0 = (tid & 7) * 32;
    const float* zp = z + (size_t)(n0 + r) * DDIM + c0;
    float v[32];
    #pragma unroll
    for (int k = 0; k < 8; ++k) {
      const float4 q = *(const float4*)(zp + 4 * k);
      v[4*k+0] = q.x; v[4*k+1] = q.y; v[4*k+2] = q.z; v[4*k+3] = q.w;
    }
    float s = 0.f;
    #pragma unroll
    for (int k = 0; k < 32; ++k) s += v[k] * v[k];
    #pragma unroll
    for (int m = 1; m < 8; m <<= 1) s += __shfl_xor(s, m, 64);
    const float scale = 16.0f / (sqrtf(s) + EPS_NORM);
    #pragma unroll
    for (int k = 0; k < 8; ++k) {
      int p = __builtin_amdgcn_cvt_pk_fp8_f32(v[4*k+0] * scale, v[4*k+1] * scale, 0, false);
      p     = __builtin_amdgcn_cvt_pk_fp8_f32(v[4*k+2] * scale, v[4*k+3] * scale, p, true);
      zs[r][c0 / 4 + k] = p;
    }
  }
  __syncthreads();

  // ---- A fragments (fp8: 2 VGPR each) ----
  long af[2][8];
  const char* zbase = (const char*)&zs[0][0];
  #pragma unroll
  for (int rg = 0; rg < 2; ++rg)
    #pragma unroll
    for (int kc = 0; kc < 8; ++kc)
      af[rg][kc] = *(const long*)(zbase + (size_t)(rg * 16 + col) * 264 + kc * 32 + quad * 8);

  const int t0    = wave * 32;
  const int ntile = (MT - t0) < 32 ? (MT - t0) : 32;   // 32,32,32,29

  // ---- sweep: S = sum(exp(sim)), M = max(c) per row; prefetched B ----
  float S[2][4] = {{0.f,0.f,0.f,0.f},{0.f,0.f,0.f,0.f}};
  float M[2][4] = {{-1e30f,-1e30f,-1e30f,-1e30f},{-1e30f,-1e30f,-1e30f,-1e30f}};
  long bn[8];
  {
    const uint8_t* bp = mnorm + (size_t)(t0 * 16 + col) * DDIM + quad * 8;
    #pragma unroll
    for (int kc = 0; kc < 8; ++kc) bn[kc] = *(const long*)(bp + kc * 32);
  }
  for (int i = 0; i < ntile; ++i) {
    long b[8];
    #pragma unroll
    for (int kc = 0; kc < 8; ++kc) b[kc] = bn[kc];
    if (i + 1 < ntile) {
      const uint8_t* bp = mnorm + (size_t)((t0 + i + 1) * 16 + col) * DDIM + quad * 8;
      #pragma unroll
      for (int kc = 0; kc < 8; ++kc) bn[kc] = *(const long*)(bp + kc * 32);
    }
    #pragma unroll
    for (int rg = 0; rg < 2; ++rg) {
      f32x4 c = (f32x4){0.f, 0.f, 0.f, 0.f};
      #pragma unroll
      for (int kc = 0; kc < 8; ++kc)
        c = __builtin_amdgcn_mfma_f32_16x16x32_fp8_fp8(af[rg][kc], b[kc], c, 0, 0, 0);
      #pragma unroll
      for (int j = 0; j < 4; ++j) {
        M[rg][j] = fmaxf(M[rg][j], c[j]);
        S[rg][j] += __expf(c[j] * INV256);
      }
    }
  }
  #pragma unroll
  for (int rg = 0; rg < 2; ++rg)
    #pragma unroll
    for (int j = 0; j < 4; ++j) {
      #pragma unroll
      for (int m = 1; m < 16; m <<= 1) {
        S[rg][j] += __shfl_xor(S[rg][j], m, 64);
        M[rg][j] = fmaxf(M[rg][j], __shfl_xor(M[rg][j], m, 64));
      }
      if (col == 0) {
        redS[wave][rg * 16 + quad * 4 + j] = S[rg][j];
        redM[wave][rg * 16 + quad * 4 + j] = M[rg][j];
      }
    }
  __syncthreads();
  if (tid < NROWS) {
    const float s = redS[0][tid] + redS[1][tid] + redS[2][tid] + redS[3][tid];
    const float m = fmaxf(fmaxf(redM[0][tid], redM[1][tid]),
                          fmaxf(redM[2][tid], redM[3][tid]));
    Srow[tid] = s;
    const float wmax = __expf(m * INV256) / s;
    if (wmax > 0.9f * LAMB) atomicOr(&anyflag, 1);   // margin; rare path exact
  }
  __syncthreads();

  if (anyflag == 0) {
    // ---- fast path: every w < lamb -> w_hat == 0, z_hat == 0 exactly ----
    const f32x4 zero4 = {0.f, 0.f, 0.f, 0.f};
    f32x4* bw = (f32x4*)(outw + (size_t)n0 * MDIM);   // 32 rows contiguous
    for (int k = tid; k < (NROWS * MDIM) / 4; k += 256)
      __builtin_nontemporal_store(zero4, bw + k);
    f32x4* bz = (f32x4*)(outz + (size_t)n0 * DDIM);
    for (int k = tid; k < (NROWS * DDIM) / 4; k += 256)
      __builtin_nontemporal_store(zero4, bz + k);
    return;
  }

  // ---- rare path (general correctness): full per-element recompute ----
  {
    const f32x4 zero4 = {0.f, 0.f, 0.f, 0.f};
    f32x4* bz = (f32x4*)(outz + (size_t)n0 * DDIM);
    for (int k = tid; k < (NROWS * DDIM) / 4; k += 256) bz[k] = zero4;
  }
  __syncthreads();
  float invS[2][4];
  #pragma unroll
  for (int rg = 0; rg < 2; ++rg)
    #pragma unroll
    for (int j = 0; j < 4; ++j) invS[rg][j] = 1.0f / Srow[rg * 16 + quad * 4 + j];

  float S2[2][4] = {{0.f,0.f,0.f,0.f},{0.f,0.f,0.f,0.f}};
  #pragma unroll 1
  for (int i = 0; i < ntile; ++i) {
    const int t = t0 + i;
    const uint8_t* bp = mnorm + (size_t)(t * 16 + col) * DDIM + quad * 8;
    long b[8];
    #pragma unroll
    for (int kc = 0; kc < 8; ++kc) b[kc] = *(const long*)(bp + kc * 32);
    #pragma unroll 1
    for (int rg = 0; rg < 2; ++rg) {
      f32x4 c = (f32x4){0.f, 0.f, 0.f, 0.f};
      #pragma unroll
      for (int kc = 0; kc < 8; ++kc)
        c = __builtin_amdgcn_mfma_f32_16x16x32_fp8_fp8(af[rg][kc], b[kc], c, 0, 0, 0);
      float* orow = outw + (size_t)(n0 + rg * 16 + quad * 4) * MDIM + t * 16 + col;
      #pragma unroll 1
      for (int j = 0; j < 4; ++j) {
        const float w = __expf(c[j] * INV256) * invS[rg][j];
        const float d = w - LAMB;
        const float w2 = (d > 0.f) ? (d * w / (d + EPS_SHRINK)) : 0.f;
        S2[rg][j] += w2;
        orow[(size_t)j * MDIM] = w2;
        if (w2 > 0.f) {
          const float* mrow = mem + (size_t)(t * 16 + col) * DDIM;
          float* zr = outz + (size_t)(n0 + rg * 16 + quad * 4 + j) * DDIM;
          #pragma unroll 1
          for (int dd = 0; dd < DDIM; ++dd) atomicAdd(&zr[dd], w2 * mrow[dd]);
        }
      }
    }
  }
  #pragma unroll
  for (int rg = 0; rg < 2; ++rg)
    #pragma unroll
    for (int j = 0; j < 4; ++j) {
      #pragma unroll
      for (int m = 1; m < 16; m <<= 1) S2[rg][j] += __shfl_xor(S2[rg][j], m, 64);
      if (col == 0) redS[wave][rg * 16 + quad * 4 + j] = S2[rg][j];
    }
  __syncthreads();
  if (tid < NROWS)
    S2row[tid] = redS[0][tid] + redS[1][tid] + redS[2][tid] + redS[3][tid];
  __syncthreads();   // also drains this block's outz atomics (block-local rows)

  // normalize outw by 1/(S2+eps) and scale outz rows likewise
  #pragma unroll 1
  for (int i = 0; i < ntile; ++i) {
    const int t = t0 + i;
    #pragma unroll 1
    for (int rg = 0; rg < 2; ++rg)
      #pragma unroll 1
      for (int j = 0; j < 4; ++j) {
        const int r = rg * 16 + quad * 4 + j;
        const float rs2 = 1.0f / (S2row[r] + EPS_SHRINK);
        float* p = outw + (size_t)(n0 + r) * MDIM + t * 16 + col;
        *p = *p * rs2;                 // rows w/ S2==0: 0 * big == 0, exact
      }
  }
  {
    const int r  = tid >> 3;
    const int c0 = (tid & 7) * 32;
    const float rs2 = 1.0f / (S2row[r] + EPS_SHRINK);
    #pragma unroll
    for (int k = 0; k < 8; ++k) {
      f32x4* p = (f32x4*)(outz + (size_t)(n0 + r) * DDIM + c0) + k;
      f32x4 v = *p;
      v *= rs2;
      *p = v;
    }
  }
}

extern "C" void kernel_launch(void* const* d_in, const int* in_sizes, int n_in,
                              void* d_out, int out_size, void* d_ws, size_t ws_size,
                              hipStream_t stream) {
  const float* z   = (const float*)d_in[0];
  const float* mem = (const float*)d_in[1];
  const int N = in_sizes[0] / DDIM;           // 65536
  float* outz = (float*)d_out;                // [N, D]
  float* outw = outz + (size_t)N * DDIM;      // [N, M]
  uint32_t* mnorm = (uint32_t*)d_ws;          // [2000, 256] fp8 = 512 KB

  hipLaunchKernelGGL(norm_mem_k, dim3(MDIM / 4), dim3(256), 0, stream, mem, mnorm);
  hipLaunchKernelGGL(fused_k, dim3(N / NROWS), dim3(256), 0, stream,
                     z, (const uint8_t*)mnorm, mem, outz, outw);
}

// Round 9
// 766.150 us; speedup vs baseline: 2.1468x; 1.0037x over previous
//
#include <hip/hip_runtime.h>
#include <stdint.h>

// MemoryModule: z[N=65536,D=256], memory[M=2000,D=256] (fp32)
//   z_norm, m_norm = row-L2-normalize (eps added to norm)
//   sim = z_norm @ m_norm^T; w = softmax(sim, axis=1)
//   w2 = relu(w-lamb)*w/(|w-lamb|+1e-12); w_hat = w2/(sum w2 + 1e-12)
//   z_hat = w_hat @ memory
// d_out = [z_hat (N*D) | w_hat (N*M)] fp32
//
// R9: R8 single fp8 sweep + threshold flag, with the block's zero-fill
// nt-stores INTERLEAVED into the sweep loop (stores issued after each
// iteration's prefetch loads, so load-waits never drain them; they retire
// in the background over the sweep). Fast path exits after the flag check.
// Rare path exact as before (reduction barrier drains fills first).

typedef float f32x4 __attribute__((ext_vector_type(4)));

#define DDIM 256
#define MDIM 2000
#define MT   125          // 2000 / 16 m-tiles (exactly, no pad tiles)
#define NROWS 32          // z-rows per block (2 row-groups of 16)
#define LAMB 0.002f
#define EPS_NORM 1e-10f
#define EPS_SHRINK 1e-12f
#define INV256 0.00390625f
// per-block zero-fill: outz 32*256/4 = 2048 vec4, outw 32*2000/4 = 16000 vec4
#define FILLV 18048
#define FILLI 71          // ceil(18048 / 256)

// ---- kernel 1: memory -> fp8 e4m3 m_norm, scaled x16. 1 row/wave ----------
__global__ __launch_bounds__(256) void norm_mem_k(const float* __restrict__ mem,
                                                  uint32_t* __restrict__ mnorm) {
  const int row  = blockIdx.x * 4 + (threadIdx.x >> 6);
  const int lane = threadIdx.x & 63;
  const float4 v = *(const float4*)(mem + (size_t)row * DDIM + lane * 4);
  float s = v.x * v.x + v.y * v.y + v.z * v.z + v.w * v.w;
  #pragma unroll
  for (int m = 1; m < 64; m <<= 1) s += __shfl_xor(s, m, 64);
  const float scale = 16.0f / (sqrtf(s) + EPS_NORM);
  int p = __builtin_amdgcn_cvt_pk_fp8_f32(v.x * scale, v.y * scale, 0, false);
  p     = __builtin_amdgcn_cvt_pk_fp8_f32(v.z * scale, v.w * scale, p, true);
  mnorm[(size_t)row * 64 + lane] = (uint32_t)p;
}

// ---- kernel 2: fused, 32 rows/block, fp8 sweep w/ interleaved zero-fill ---
// 4 waves split 125 m-tiles contiguously (32/32/32/29). Per tile: B[8]
// (16 rows x K=256 fp8) from L2 w/ prefetch, 16 MFMA fp8 vs 2 row-groups.
// MFMA C layout (16x16x32): col = lane&15 (m), row = quad*4 + reg (n).
__global__ __launch_bounds__(256, 4) void fused_k(
    const float* __restrict__ z, const uint8_t* __restrict__ mnorm,
    const float* __restrict__ mem, float* __restrict__ outz,
    float* __restrict__ outw) {
  __shared__ int   zs[NROWS][66];     // fp8 z_norm x16; 264B rows (8-aligned)
  __shared__ float redS[4][NROWS];
  __shared__ float redM[4][NROWS];
  __shared__ float Srow[NROWS];
  __shared__ float S2row[NROWS];
  __shared__ int   anyflag;

  const int tid  = threadIdx.x;
  const int n0   = blockIdx.x * NROWS;
  const int lane = tid & 63;
  const int wave = tid >> 6;
  const int quad = lane >> 4;
  const int col  = lane & 15;

  if (tid == 0) anyflag = 0;

  // ---- phase 1: z_norm -> zs as fp8 x16 ----
  {
    const int r  = tid >> 3;
    const int c0 = (tid & 7) * 32;
    const float* zp = z + (size_t)(n0 + r) * DDIM + c0;
    float v[32];
    #pragma unroll
    for (int k = 0; k < 8; ++k) {
      const float4 q = *(const float4*)(zp + 4 * k);
      v[4*k+0] = q.x; v[4*k+1] = q.y; v[4*k+2] = q.z; v[4*k+3] = q.w;
    }
    float s = 0.f;
    #pragma unroll
    for (int k = 0; k < 32; ++k) s += v[k] * v[k];
    #pragma unroll
    for (int m = 1; m < 8; m <<= 1) s += __shfl_xor(s, m, 64);
    const float scale = 16.0f / (sqrtf(s) + EPS_NORM);
    #pragma unroll
    for (int k = 0; k < 8; ++k) {
      int p = __builtin_amdgcn_cvt_pk_fp8_f32(v[4*k+0] * scale, v[4*k+1] * scale, 0, false);
      p     = __builtin_amdgcn_cvt_pk_fp8_f32(v[4*k+2] * scale, v[4*k+3] * scale, p, true);
      zs[r][c0 / 4 + k] = p;
    }
  }
  __syncthreads();

  // ---- A fragments (fp8: 2 VGPR each) ----
  long af[2][8];
  const char* zbase = (const char*)&zs[0][0];
  #pragma unroll
  for (int rg = 0; rg < 2; ++rg)
    #pragma unroll
    for (int kc = 0; kc < 8; ++kc)
      af[rg][kc] = *(const long*)(zbase + (size_t)(rg * 16 + col) * 264 + kc * 32 + quad * 8);

  const int t0    = wave * 32;
  const int ntile = (MT - t0) < 32 ? (MT - t0) : 32;   // 32,32,32,29

  f32x4* bz4 = (f32x4*)(outz + (size_t)n0 * DDIM);   // 2048 vec4
  f32x4* bw4 = (f32x4*)(outw + (size_t)n0 * MDIM);   // 16000 vec4
  const f32x4 zero4 = {0.f, 0.f, 0.f, 0.f};

  // ---- sweep: S = sum(exp(sim)), M = max(c) per row; prefetched B;
  //      zero-fill stores interleaved (after loads -> never block vmcnt) ----
  float S[2][4] = {{0.f,0.f,0.f,0.f},{0.f,0.f,0.f,0.f}};
  float M[2][4] = {{-1e30f,-1e30f,-1e30f,-1e30f},{-1e30f,-1e30f,-1e30f,-1e30f}};
  long bn[8];
  {
    const uint8_t* bp = mnorm + (size_t)(t0 * 16 + col) * DDIM + quad * 8;
    #pragma unroll
    for (int kc = 0; kc < 8; ++kc) bn[kc] = *(const long*)(bp + kc * 32);
  }
  for (int i = 0; i < FILLI; ++i) {
    long b[8];
    if (i < ntile) {                      // wave-uniform
      #pragma unroll
      for (int kc = 0; kc < 8; ++kc) b[kc] = bn[kc];
      if (i + 1 < ntile) {
        const uint8_t* bp = mnorm + (size_t)((t0 + i + 1) * 16 + col) * DDIM + quad * 8;
        #pragma unroll
        for (int kc = 0; kc < 8; ++kc) bn[kc] = *(const long*)(bp + kc * 32);
      }
    }
    // zero-fill share for this iteration (issued after this iter's loads)
    {
      const int vi = i * 256 + tid;
      if (vi < FILLV) {
        f32x4* addr = (vi < 2048) ? (bz4 + vi) : (bw4 + (vi - 2048));
        __builtin_nontemporal_store(zero4, addr);
      }
    }
    if (i < ntile) {
      #pragma unroll
      for (int rg = 0; rg < 2; ++rg) {
        f32x4 c = (f32x4){0.f, 0.f, 0.f, 0.f};
        #pragma unroll
        for (int kc = 0; kc < 8; ++kc)
          c = __builtin_amdgcn_mfma_f32_16x16x32_fp8_fp8(af[rg][kc], b[kc], c, 0, 0, 0);
        #pragma unroll
        for (int j = 0; j < 4; ++j) {
          M[rg][j] = fmaxf(M[rg][j], c[j]);
          S[rg][j] += __expf(c[j] * INV256);
        }
      }
    }
  }
  #pragma unroll
  for (int rg = 0; rg < 2; ++rg)
    #pragma unroll
    for (int j = 0; j < 4; ++j) {
      #pragma unroll
      for (int m = 1; m < 16; m <<= 1) {
        S[rg][j] += __shfl_xor(S[rg][j], m, 64);
        M[rg][j] = fmaxf(M[rg][j], __shfl_xor(M[rg][j], m, 64));
      }
      if (col == 0) {
        redS[wave][rg * 16 + quad * 4 + j] = S[rg][j];
        redM[wave][rg * 16 + quad * 4 + j] = M[rg][j];
      }
    }
  __syncthreads();
  if (tid < NROWS) {
    const float s = redS[0][tid] + redS[1][tid] + redS[2][tid] + redS[3][tid];
    const float m = fmaxf(fmaxf(redM[0][tid], redM[1][tid]),
                          fmaxf(redM[2][tid], redM[3][tid]));
    Srow[tid] = s;
    const float wmax = __expf(m * INV256) / s;
    if (wmax > 0.9f * LAMB) atomicOr(&anyflag, 1);   // margin; rare path exact
  }
  __syncthreads();   // also drains this block's zero-fill stores

  if (anyflag == 0) return;   // fast path: zeros already written, exact

  // ---- rare path (general correctness): full per-element recompute.
  // outz is already zeroed; fill stores drained by the barrier above. ----
  float invS[2][4];
  #pragma unroll
  for (int rg = 0; rg < 2; ++rg)
    #pragma unroll
    for (int j = 0; j < 4; ++j) invS[rg][j] = 1.0f / Srow[rg * 16 + quad * 4 + j];

  float S2[2][4] = {{0.f,0.f,0.f,0.f},{0.f,0.f,0.f,0.f}};
  #pragma unroll 1
  for (int i = 0; i < ntile; ++i) {
    const int t = t0 + i;
    const uint8_t* bp = mnorm + (size_t)(t * 16 + col) * DDIM + quad * 8;
    long b[8];
    #pragma unroll
    for (int kc = 0; kc < 8; ++kc) b[kc] = *(const long*)(bp + kc * 32);
    #pragma unroll 1
    for (int rg = 0; rg < 2; ++rg) {
      f32x4 c = (f32x4){0.f, 0.f, 0.f, 0.f};
      #pragma unroll
      for (int kc = 0; kc < 8; ++kc)
        c = __builtin_amdgcn_mfma_f32_16x16x32_fp8_fp8(af[rg][kc], b[kc], c, 0, 0, 0);
      float* orow = outw + (size_t)(n0 + rg * 16 + quad * 4) * MDIM + t * 16 + col;
      #pragma unroll 1
      for (int j = 0; j < 4; ++j) {
        const float w = __expf(c[j] * INV256) * invS[rg][j];
        const float d = w - LAMB;
        const float w2 = (d > 0.f) ? (d * w / (d + EPS_SHRINK)) : 0.f;
        S2[rg][j] += w2;
        orow[(size_t)j * MDIM] = w2;
        if (w2 > 0.f) {
          const float* mrow = mem + (size_t)(t * 16 + col) * DDIM;
          float* zr = outz + (size_t)(n0 + rg * 16 + quad * 4 + j) * DDIM;
          #pragma unroll 1
          for (int dd = 0; dd < DDIM; ++dd) atomicAdd(&zr[dd], w2 * mrow[dd]);
        }
      }
    }
  }
  #pragma unroll
  for (int rg = 0; rg < 2; ++rg)
    #pragma unroll
    for (int j = 0; j < 4; ++j) {
      #pragma unroll
      for (int m = 1; m < 16; m <<= 1) S2[rg][j] += __shfl_xor(S2[rg][j], m, 64);
      if (col == 0) redS[wave][rg * 16 + quad * 4 + j] = S2[rg][j];
    }
  __syncthreads();
  if (tid < NROWS)
    S2row[tid] = redS[0][tid] + redS[1][tid] + redS[2][tid] + redS[3][tid];
  __syncthreads();   // also drains this block's outz atomics (block-local rows)

  // normalize outw by 1/(S2+eps) and scale outz rows likewise
  #pragma unroll 1
  for (int i = 0; i < ntile; ++i) {
    const int t = t0 + i;
    #pragma unroll 1
    for (int rg = 0; rg < 2; ++rg)
      #pragma unroll 1
      for (int j = 0; j < 4; ++j) {
        const int r = rg * 16 + quad * 4 + j;
        const float rs2 = 1.0f / (S2row[r] + EPS_SHRINK);
        float* p = outw + (size_t)(n0 + r) * MDIM + t * 16 + col;
        *p = *p * rs2;                 // rows w/ S2==0: 0 * big == 0, exact
      }
  }
  {
    const int r  = tid >> 3;
    const int c0 = (tid & 7) * 32;
    const float rs2 = 1.0f / (S2row[r] + EPS_SHRINK);
    #pragma unroll
    for (int k = 0; k < 8; ++k) {
      f32x4* p = (f32x4*)(outz + (size_t)(n0 + r) * DDIM + c0) + k;
      f32x4 v = *p;
      v *= rs2;
      *p = v;
    }
  }
}

extern "C" void kernel_launch(void* const* d_in, const int* in_sizes, int n_in,
                              void* d_out, int out_size, void* d_ws, size_t ws_size,
                              hipStream_t stream) {
  const float* z   = (const float*)d_in[0];
  const float* mem = (const float*)d_in[1];
  const int N = in_sizes[0] / DDIM;           // 65536
  float* outz = (float*)d_out;                // [N, D]
  float* outw = outz + (size_t)N * DDIM;      // [N, M]
  uint32_t* mnorm = (uint32_t*)d_ws;          // [2000, 256] fp8 = 512 KB

  hipLaunchKernelGGL(norm_mem_k, dim3(MDIM / 4), dim3(256), 0, stream, mem, mnorm);
  hipLaunchKernelGGL(fused_k, dim3(N / NROWS), dim3(256), 0, stream,
                     z, (const uint8_t*)mnorm, mem, outz, outw);
}